// Round 5
// baseline (1113.981 us; speedup 1.0000x reference)
//
#include <hip/hip_runtime.h>

#define BATCH 8
#define NPTS 4096
#define NSAMP 512   // npoint = NPTS/8

#define ROW_SHR(n) (0x110 | (n))
#define ROW_BCAST15 0x142
#define ROW_BCAST31 0x143

// f32 max-combine via DPP (1 mov_dpp + 1 v_max_f32). bound_ctrl/row_mask
// holes deliver 0.0f, identity for distances >= 0.
template <int CTRL, int RMASK>
__device__ __forceinline__ float fmax_dpp(float x) {
  int t = __builtin_amdgcn_update_dpp(0, __float_as_int(x), CTRL, RMASK, 0xf, true);
  return fmaxf(x, __int_as_float(t));
}

// ---------------------------------------------------------------------------
// Kernel A: farthest point sampling. One block per batch, 512 threads,
// 8 points per thread (thread t owns [8t, 8t+8) => lane order == index
// order, wave order == index order). Exact fp32 (no FMA contraction) so
// the argmax selection matches numpy bit-for-bit; ties resolve to the
// smallest index exactly like np.argmax.
// ---------------------------------------------------------------------------
__global__ __launch_bounds__(512) void fps_kernel(const float* __restrict__ pcd,
                                                  float* __restrict__ new_xyz) {
  __shared__ float4 s_pts[NPTS];   // 64 KB coord table for winner gather
  __shared__ float4 slot[2][8];    // per-wave winner (x,y,z,val), parity dbuf

  const int b = blockIdx.x;
  const int t = threadIdx.x;
  const int wave = t >> 6;
  const int lane = t & 63;
  const float* xb = pcd + (size_t)b * NPTS * 3;

  float X[8], Y[8], Z[8], mind[8];
  {
    float v[24];
    float4* vv = (float4*)v;
    const float4* src = (const float4*)xb + t * 6;   // 96B/thread, coalesced
#pragma unroll
    for (int q = 0; q < 6; ++q) vv[q] = src[q];
#pragma unroll
    for (int j = 0; j < 8; ++j) {
      X[j] = v[3 * j + 0]; Y[j] = v[3 * j + 1]; Z[j] = v[3 * j + 2];
      mind[j] = 10000000000.0f;
      s_pts[t * 8 + j] = make_float4(X[j], Y[j], Z[j], 0.0f);
    }
  }
  __syncthreads();

  float px = xb[0], py = xb[1], pz = xb[2];   // first sample is index 0

  for (int it = 0; it < NSAMP; ++it) {
    if (t == 0) {
      size_t o = ((size_t)b * NSAMP + it) * 3;
      new_xyz[o + 0] = px; new_xyz[o + 1] = py; new_xyz[o + 2] = pz;
    }
    // ---- update min-dist + local argmax (strict > = first occurrence) ----
    float bv = -1.0f; int bi = 0;
#pragma unroll
    for (int j = 0; j < 8; ++j) {
      float dx = __fsub_rn(X[j], px);
      float dy = __fsub_rn(Y[j], py);
      float dz = __fsub_rn(Z[j], pz);
      float d = __fadd_rn(__fadd_rn(__fmul_rn(dx, dx), __fmul_rn(dy, dy)),
                          __fmul_rn(dz, dz));
      float m = fminf(mind[j], d);
      mind[j] = m;
      bool g = m > bv;
      bv = g ? m : bv;
      bi = g ? t * 8 + j : bi;
    }
    // ---- wave max via f32 DPP; ballot+ffs -> exact lowest-index winner ---
    float m6 = bv;
    m6 = fmax_dpp<ROW_SHR(1), 0xf>(m6);
    m6 = fmax_dpp<ROW_SHR(2), 0xf>(m6);
    m6 = fmax_dpp<ROW_SHR(4), 0xf>(m6);
    m6 = fmax_dpp<ROW_SHR(8), 0xf>(m6);
    m6 = fmax_dpp<ROW_BCAST15, 0xa>(m6);
    m6 = fmax_dpp<ROW_BCAST31, 0xc>(m6);
    float wmax = __int_as_float(
        __builtin_amdgcn_readlane(__float_as_int(m6), 63));
    unsigned long long msk = __ballot(bv == wmax);
    if (lane == __ffsll(msk) - 1) {
      float4 p = s_pts[bi];
      p.w = wmax;
      slot[it & 1][wave] = p;
    }
    __syncthreads();
    // ---- cross-wave combine; strict > keeps lowest wave = lowest index ---
    float4 cur = slot[it & 1][0];
#pragma unroll
    for (int w = 1; w < 8; ++w) {
      float4 sw = slot[it & 1][w];
      if (sw.w > cur.w) cur = sw;
    }
    px = cur.x; py = cur.y; pz = cur.z;
  }
}

// ---------------------------------------------------------------------------
// Weight prep: transpose each w[cin][cout] into wt[cout][cinp] (cin padded
// to a multiple of 4 with zeros) so MLP threads can float4-load weights.
// ---------------------------------------------------------------------------
__device__ __forceinline__ void tsec(int g, const float* __restrict__ w,
                                     float* __restrict__ wt, int cin, int cinp,
                                     int cout, int base) {
  int local = g - base;
  if (local < 0 || local >= cinp * cout) return;
  int oc = local / cinp, ic = local % cinp;
  wt[base + local] = (ic < cin) ? w[ic * cout + oc] : 0.0f;
}

#define W00 0
#define W01 128
#define W02 1152
#define W10 3200
#define W11 3456
#define W12 7552
#define W20 15744
#define W21 16000
#define W22 22144
#define WT_TOTAL 34432

__global__ __launch_bounds__(256) void prep_kernel(
    const float* w00, const float* w01, const float* w02,
    const float* w10, const float* w11, const float* w12,
    const float* w20, const float* w21, const float* w22,
    float* __restrict__ wt) {
  int g = blockIdx.x * 256 + threadIdx.x;
  tsec(g, w00, wt, 3, 4, 32, W00);
  tsec(g, w01, wt, 32, 32, 32, W01);
  tsec(g, w02, wt, 32, 32, 64, W02);
  tsec(g, w10, wt, 3, 4, 64, W10);
  tsec(g, w11, wt, 64, 64, 64, W11);
  tsec(g, w12, wt, 64, 64, 128, W12);
  tsec(g, w20, wt, 3, 4, 64, W20);
  tsec(g, w21, wt, 64, 64, 96, W21);
  tsec(g, w22, wt, 96, 96, 128, W22);
}

// ---------------------------------------------------------------------------
// Tiled MLP layer, transposed weights: block = 16 n-threads x 16 oc-threads.
// h channel-major in LDS with padded row stride NTP. Register discipline:
// c4 loop NOT unrolled, single float4 weight register live at a time
// (r4's wv[TOC] array caused spills -> 45 MB scratch traffic).
// FINAL: fuse bias+relu+max-over-n via LDS int atomicMax (vals >= 0).
// ---------------------------------------------------------------------------
template <int CINP, int COUT, int NT, int NTP, bool FINAL>
__device__ __forceinline__ void layerT(const float* __restrict__ wt,
                                       const float* __restrict__ bias,
                                       const float* hin, float* hout, int tid) {
  constexpr int TN = NT / 16;
  constexpr int TOC = COUT / 16;
  const int tn = tid & 15, toc = tid >> 4;
  float acc[TOC][TN];
#pragma unroll
  for (int j = 0; j < TOC; ++j) {
    float bj = bias[toc * TOC + j];
#pragma unroll
    for (int i = 0; i < TN; ++i) acc[j][i] = bj;
  }
#pragma unroll 1
  for (int c4 = 0; c4 < CINP / 4; ++c4) {
    float hv[4][TN];
#pragma unroll
    for (int k = 0; k < 4; ++k) {
      if (TN == 2) {
        float2 h2 = *(const float2*)&hin[(c4 * 4 + k) * NTP + tn * 2];
        hv[k][0] = h2.x; hv[k][TN - 1] = h2.y;
      } else {
#pragma unroll
        for (int i = 0; i < TN; ++i)
          hv[k][i] = hin[(c4 * 4 + k) * NTP + tn * TN + i];
      }
    }
#pragma unroll
    for (int j = 0; j < TOC; ++j) {
      float4 w4 = *(const float4*)&wt[(toc * TOC + j) * CINP + c4 * 4];
#pragma unroll
      for (int i = 0; i < TN; ++i) {
        acc[j][i] = fmaf(hv[0][i], w4.x, acc[j][i]);
        acc[j][i] = fmaf(hv[1][i], w4.y, acc[j][i]);
        acc[j][i] = fmaf(hv[2][i], w4.z, acc[j][i]);
        acc[j][i] = fmaf(hv[3][i], w4.w, acc[j][i]);
      }
    }
  }
  if (FINAL) {
#pragma unroll
    for (int j = 0; j < TOC; ++j) {
      float mx = 0.0f;  // relu floor
#pragma unroll
      for (int i = 0; i < TN; ++i) mx = fmaxf(mx, acc[j][i]);
      atomicMax((int*)&hout[toc * TOC + j], __float_as_int(mx));
    }
  } else {
#pragma unroll
    for (int j = 0; j < TOC; ++j) {
      if (TN == 2) {
        float2 v = make_float2(fmaxf(acc[j][0], 0.0f),
                               fmaxf(acc[j][TN - 1], 0.0f));
        *(float2*)&hout[(toc * TOC + j) * NTP + tn * 2] = v;
      } else {
#pragma unroll
        for (int i = 0; i < TN; ++i)
          hout[(toc * TOC + j) * NTP + tn * TN + i] = fmaxf(acc[j][i], 0.0f);
      }
    }
  }
}

// ---------------------------------------------------------------------------
// Kernel B: one block per (b, s) sample point.
// Phase 1: all 256 threads build per-chunk in-radius bitmasks for all 3
// radii (16 rounds). Phase 2: wave s walks scale-s masks to build its
// ordered index list. Phase 3: per-scale MLP + max (NT=32 tiles).
// ---------------------------------------------------------------------------
__global__ __launch_bounds__(256) void msg_kernel(
    const float* __restrict__ pcd, const float* __restrict__ new_xyz,
    const float* __restrict__ wt,
    const float* __restrict__ b00, const float* __restrict__ b01,
    const float* __restrict__ b02, const float* __restrict__ b10,
    const float* __restrict__ b11, const float* __restrict__ b12,
    const float* __restrict__ b20, const float* __restrict__ b21,
    const float* __restrict__ b22,
    const float* __restrict__ wf, const float* __restrict__ bf,
    float* __restrict__ out) {
  __shared__ float hA[96 * 34];                  // 13056 B
  __shared__ float hB[64 * 34];                  //  8704 B
  __shared__ unsigned long long masks[3][64];    //  1536 B
  __shared__ int lists[176];                     // 16 + 32 + 128
  __shared__ float feat[320];

  const int bs = blockIdx.x;
  const int b = bs >> 9;
  const int tid = threadIdx.x;
  const int lane = tid & 63;
  const int wave = tid >> 6;
  const float* xb = pcd + (size_t)b * NPTS * 3;

  const float cx = new_xyz[(size_t)bs * 3 + 0];
  const float cy = new_xyz[(size_t)bs * 3 + 1];
  const float cz = new_xyz[(size_t)bs * 3 + 2];

  for (int c = tid; c < 320; c += 256) feat[c] = 0.0f;

  // ---- phase 1: all threads, 16 rounds, 3 ballots each -> 192 masks ----
  const float r2a = (float)(0.1 * 0.1);
  const float r2b = (float)(0.2 * 0.2);
  const float r2c = (float)(0.4 * 0.4);
#pragma unroll 4
  for (int j = 0; j < 16; ++j) {
    int i = (j << 8) | tid;
    const float* p = xb + i * 3;
    float dx = __fsub_rn(cx, p[0]);
    float dy = __fsub_rn(cy, p[1]);
    float dz = __fsub_rn(cz, p[2]);
    float sq = __fadd_rn(__fadd_rn(__fmul_rn(dx, dx), __fmul_rn(dy, dy)),
                         __fmul_rn(dz, dz));
    unsigned long long m0 = __ballot(sq < r2a);
    unsigned long long m1 = __ballot(sq < r2b);
    unsigned long long m2 = __ballot(sq < r2c);
    if (lane == 0) {
      int c = (j << 2) | wave;
      masks[0][c] = m0; masks[1][c] = m1; masks[2][c] = m2;
    }
  }
  __syncthreads();

  // ---- phase 2: wave s builds ordered list for scale s ----
  if (wave < 3) {
    const int ns  = (wave == 0) ? 16 : (wave == 1) ? 32 : 128;
    const int off = (wave == 0) ? 0  : (wave == 1) ? 16 : 48;
    int cnt = 0;
    for (int c = 0; c < 64; ++c) {
      unsigned long long m = masks[wave][c];
      if (m) {
        int bit = (int)((m >> lane) & 1ull);
        int pos = cnt + (int)__popcll(m & ((1ull << lane) - 1ull));
        if (bit && pos < ns) lists[off + pos] = (c << 6) | lane;
        cnt += (int)__popcll(m);
        if (cnt >= ns) break;
      }
    }
    if (cnt > ns) cnt = ns;
    int first = lists[off];              // center is always in-radius
    for (int k = cnt + lane; k < ns; k += 64) lists[off + k] = first;
  }
  __syncthreads();

  // ---- scale 0: ns=16, 3->32->32->64 -> feat[0:64) ----
  {
    if (tid < 16) {
      int j = lists[tid];
      const float* p = xb + j * 3;
      hA[0 * 18 + tid] = __fsub_rn(p[0], cx);
      hA[1 * 18 + tid] = __fsub_rn(p[1], cy);
      hA[2 * 18 + tid] = __fsub_rn(p[2], cz);
      hA[3 * 18 + tid] = 0.0f;
    }
    __syncthreads();
    layerT<4, 32, 16, 18, false>(wt + W00, b00, hA, hB, tid);  __syncthreads();
    layerT<32, 32, 16, 18, false>(wt + W01, b01, hB, hA, tid); __syncthreads();
    layerT<32, 64, 16, 18, true>(wt + W02, b02, hA, feat + 0, tid);
    __syncthreads();
  }
  // ---- scale 1: ns=32, 3->64->64->128 -> feat[64:192) ----
  {
    if (tid < 32) {
      int j = lists[16 + tid];
      const float* p = xb + j * 3;
      hA[0 * 34 + tid] = __fsub_rn(p[0], cx);
      hA[1 * 34 + tid] = __fsub_rn(p[1], cy);
      hA[2 * 34 + tid] = __fsub_rn(p[2], cz);
      hA[3 * 34 + tid] = 0.0f;
    }
    __syncthreads();
    layerT<4, 64, 32, 34, false>(wt + W10, b10, hA, hB, tid);  __syncthreads();
    layerT<64, 64, 32, 34, false>(wt + W11, b11, hB, hA, tid); __syncthreads();
    layerT<64, 128, 32, 34, true>(wt + W12, b12, hA, feat + 64, tid);
    __syncthreads();
  }
  // ---- scale 2: ns=128 in 4 tiles of 32, 3->64->96->128 -> feat[192:320) --
  for (int tile = 0; tile < 4; ++tile) {
    if (tid < 32) {
      int j = lists[48 + tile * 32 + tid];
      const float* p = xb + j * 3;
      hA[0 * 34 + tid] = __fsub_rn(p[0], cx);
      hA[1 * 34 + tid] = __fsub_rn(p[1], cy);
      hA[2 * 34 + tid] = __fsub_rn(p[2], cz);
      hA[3 * 34 + tid] = 0.0f;
    }
    __syncthreads();
    layerT<4, 64, 32, 34, false>(wt + W20, b20, hA, hB, tid);  __syncthreads();
    layerT<64, 96, 32, 34, false>(wt + W21, b21, hB, hA, tid); __syncthreads();
    layerT<96, 128, 32, 34, true>(wt + W22, b22, hA, feat + 192, tid);
    __syncthreads();
  }

  // ---- final linear 320 -> 1 ----
  if (tid < 64) {
    float s = 0.0f;
#pragma unroll
    for (int c = 0; c < 5; ++c) s += feat[tid + c * 64] * wf[tid + c * 64];
#pragma unroll
    for (int o = 32; o > 0; o >>= 1) s += __shfl_down(s, o);
    if (tid == 0) out[bs] = s + bf[0];
  }
}

extern "C" void kernel_launch(void* const* d_in, const int* in_sizes, int n_in,
                              void* d_out, int out_size, void* d_ws, size_t ws_size,
                              hipStream_t stream) {
  const float* pcd = (const float*)d_in[0];
  float* wsf = (float*)d_ws;
  float* new_xyz = wsf;                 // 8*512*3 = 12288 floats (48 KB)
  float* wt = wsf + 12288;              // 34432 floats (transposed weights)

  prep_kernel<<<(WT_TOTAL + 255) / 256, 256, 0, stream>>>(
      (const float*)d_in[1], (const float*)d_in[3], (const float*)d_in[5],
      (const float*)d_in[7], (const float*)d_in[9], (const float*)d_in[11],
      (const float*)d_in[13], (const float*)d_in[15], (const float*)d_in[17],
      wt);

  fps_kernel<<<BATCH, 512, 0, stream>>>(pcd, new_xyz);

  msg_kernel<<<BATCH * NSAMP, 256, 0, stream>>>(
      pcd, new_xyz, wt,
      (const float*)d_in[2],  (const float*)d_in[4],  (const float*)d_in[6],
      (const float*)d_in[8],  (const float*)d_in[10], (const float*)d_in[12],
      (const float*)d_in[14], (const float*)d_in[16], (const float*)d_in[18],
      (const float*)d_in[19], (const float*)d_in[20],
      (float*)d_out);
}

// Round 6
// 830.816 us; speedup vs baseline: 1.3408x; 1.3408x over previous
//
#include <hip/hip_runtime.h>

#define BATCH 8
#define NPTS 4096
#define NSAMP 512   // npoint = NPTS/8

#define ROW_SHR(n) (0x110 | (n))
#define ROW_BCAST15 0x142
#define ROW_BCAST31 0x143

// one max-combine step on a packed u64 key via DPP (VALU latency, no LDS).
// CTRL/RMASK are template params: __builtin_amdgcn_update_dpp needs ICEs.
template <int CTRL, int RMASK>
__device__ __forceinline__ unsigned long long kmax_dpp(unsigned long long k) {
  unsigned lo = (unsigned)__builtin_amdgcn_update_dpp(0, (int)(unsigned)k,
                                                      CTRL, RMASK, 0xf, true);
  unsigned hi = (unsigned)__builtin_amdgcn_update_dpp(0, (int)(unsigned)(k >> 32),
                                                      CTRL, RMASK, 0xf, true);
  unsigned long long o = ((unsigned long long)hi << 32) | lo;
  return o > k ? o : k;   // masked/OOB lanes deliver 0 -> identity
}

// ---------------------------------------------------------------------------
// Kernel A: farthest point sampling (r3 version — best measured ~250 us).
// One block per batch, 256 threads. Exact fp32 (no FMA contraction) so the
// argmax selection matches numpy bit-for-bit. Packed key:
// (float_bits(val) << 32) | ~idx  => u64-max == (max val, tie -> smaller idx).
// ---------------------------------------------------------------------------
__global__ __launch_bounds__(256) void fps_kernel(const float* __restrict__ pcd,
                                                  float* __restrict__ new_xyz) {
  __shared__ float4 s_pts[NPTS];                       // 64 KB
  __shared__ unsigned long long red[2][4];             // parity double-buffer

  const int b = blockIdx.x;
  const int t = threadIdx.x;
  const int wave = t >> 6;
  const int lane = t & 63;
  const float* xb = pcd + (size_t)b * NPTS * 3;

  float X[16], Y[16], Z[16], mind[16];
#pragma unroll
  for (int j = 0; j < 16; ++j) {
    int i = t + 256 * j;
    float x = xb[i * 3 + 0], y = xb[i * 3 + 1], z = xb[i * 3 + 2];
    X[j] = x; Y[j] = y; Z[j] = z;
    s_pts[i] = make_float4(x, y, z, 0.0f);
    mind[j] = 10000000000.0f;
  }
  __syncthreads();

  float px = xb[0], py = xb[1], pz = xb[2];            // idx 0 is first sample

  for (int it = 0; it < NSAMP; ++it) {
    if (t == 0) {
      size_t o = ((size_t)b * NSAMP + it) * 3;
      new_xyz[o + 0] = px; new_xyz[o + 1] = py; new_xyz[o + 2] = pz;
    }
    float bv = -1.0f; int bi = 0;
#pragma unroll
    for (int j = 0; j < 16; ++j) {
      float dx = __fsub_rn(X[j], px);
      float dy = __fsub_rn(Y[j], py);
      float dz = __fsub_rn(Z[j], pz);
      float d = __fadd_rn(__fadd_rn(__fmul_rn(dx, dx), __fmul_rn(dy, dy)),
                          __fmul_rn(dz, dz));
      float m = fminf(mind[j], d);
      mind[j] = m;
      if (m > bv) { bv = m; bi = t + 256 * j; }        // strict >: first occ.
    }
    unsigned long long key =
        ((unsigned long long)__float_as_uint(bv) << 32) |
        (unsigned long long)(~(unsigned)bi);
    key = kmax_dpp<ROW_SHR(1), 0xf>(key);
    key = kmax_dpp<ROW_SHR(2), 0xf>(key);
    key = kmax_dpp<ROW_SHR(4), 0xf>(key);
    key = kmax_dpp<ROW_SHR(8), 0xf>(key);
    key = kmax_dpp<ROW_BCAST15, 0xa>(key);
    key = kmax_dpp<ROW_BCAST31, 0xc>(key);
    unsigned wlo = (unsigned)__builtin_amdgcn_readlane((int)(unsigned)key, 63);
    unsigned whi = (unsigned)__builtin_amdgcn_readlane((int)(unsigned)(key >> 32), 63);
    if (lane == 0)
      red[it & 1][wave] = ((unsigned long long)whi << 32) | wlo;
    __syncthreads();
    unsigned long long g = red[it & 1][0];
    unsigned long long g1 = red[it & 1][1];
    unsigned long long g2 = red[it & 1][2];
    unsigned long long g3 = red[it & 1][3];
    if (g1 > g) g = g1;
    if (g2 > g) g = g2;
    if (g3 > g) g = g3;
    int nxt = (int)(~(unsigned)g);
    float4 p = s_pts[nxt];
    px = p.x; py = p.y; pz = p.z;
  }
}

// ---------------------------------------------------------------------------
// Weight prep: transpose each w[cin][cout] into wt[cout][cinp] (cin padded
// to a multiple of 4 with zeros) so MLP threads can float4-load weights.
// ---------------------------------------------------------------------------
__device__ __forceinline__ void tsec(int g, const float* __restrict__ w,
                                     float* __restrict__ wt, int cin, int cinp,
                                     int cout, int base) {
  int local = g - base;
  if (local < 0 || local >= cinp * cout) return;
  int oc = local / cinp, ic = local % cinp;
  wt[base + local] = (ic < cin) ? w[ic * cout + oc] : 0.0f;
}

#define W00 0
#define W01 128
#define W02 1152
#define W10 3200
#define W11 3456
#define W12 7552
#define W20 15744
#define W21 16000
#define W22 22144
#define WT_TOTAL 34432

__global__ __launch_bounds__(256) void prep_kernel(
    const float* w00, const float* w01, const float* w02,
    const float* w10, const float* w11, const float* w12,
    const float* w20, const float* w21, const float* w22,
    float* __restrict__ wt) {
  int g = blockIdx.x * 256 + threadIdx.x;
  tsec(g, w00, wt, 3, 4, 32, W00);
  tsec(g, w01, wt, 32, 32, 32, W01);
  tsec(g, w02, wt, 32, 32, 64, W02);
  tsec(g, w10, wt, 3, 4, 64, W10);
  tsec(g, w11, wt, 64, 64, 64, W11);
  tsec(g, w12, wt, 64, 64, 128, W12);
  tsec(g, w20, wt, 3, 4, 64, W20);
  tsec(g, w21, wt, 64, 64, 96, W21);
  tsec(g, w22, wt, 96, 96, 128, W22);
}

// ---------------------------------------------------------------------------
// Tiled MLP layer, transposed weights: block = 16 n-threads x 16 oc-threads.
// h channel-major in LDS, padded row stride NTP. c4 loop unroll 2 for
// software pipelining; exactly one float4 weight register live per j
// (r4's wv[TOC] array spilled). FINAL: bias+relu+max via LDS int atomicMax.
// ---------------------------------------------------------------------------
template <int CINP, int COUT, int NT, int NTP, bool FINAL>
__device__ __forceinline__ void layerT(const float* __restrict__ wt,
                                       const float* __restrict__ bias,
                                       const float* hin, float* hout, int tid) {
  constexpr int TN = NT / 16;
  constexpr int TOC = COUT / 16;
  const int tn = tid & 15, toc = tid >> 4;
  float acc[TOC][TN];
#pragma unroll
  for (int j = 0; j < TOC; ++j) {
    float bj = bias[toc * TOC + j];
#pragma unroll
    for (int i = 0; i < TN; ++i) acc[j][i] = bj;
  }
#pragma unroll 2
  for (int c4 = 0; c4 < CINP / 4; ++c4) {
    float hv[4][TN];
#pragma unroll
    for (int k = 0; k < 4; ++k) {
      const float* src = &hin[(c4 * 4 + k) * NTP + tn * TN];
      if (TN == 1) {
        hv[k][0] = src[0];
      } else if (TN == 2) {
        float2 v = *(const float2*)src;
        hv[k][0] = v.x; hv[k][TN > 1 ? 1 : 0] = v.y;
      } else {
        float4 v = *(const float4*)src;
        hv[k][0] = v.x;
        hv[k][TN > 1 ? 1 : 0] = v.y;
        hv[k][TN > 2 ? 2 : 0] = v.z;
        hv[k][TN > 3 ? 3 : 0] = v.w;
      }
    }
#pragma unroll
    for (int j = 0; j < TOC; ++j) {
      float4 w4 = *(const float4*)&wt[(toc * TOC + j) * CINP + c4 * 4];
#pragma unroll
      for (int i = 0; i < TN; ++i) {
        acc[j][i] = fmaf(hv[0][i], w4.x, acc[j][i]);
        acc[j][i] = fmaf(hv[1][i], w4.y, acc[j][i]);
        acc[j][i] = fmaf(hv[2][i], w4.z, acc[j][i]);
        acc[j][i] = fmaf(hv[3][i], w4.w, acc[j][i]);
      }
    }
  }
  if (FINAL) {
#pragma unroll
    for (int j = 0; j < TOC; ++j) {
      float mx = 0.0f;  // relu floor
#pragma unroll
      for (int i = 0; i < TN; ++i) mx = fmaxf(mx, acc[j][i]);
      atomicMax((int*)&hout[toc * TOC + j], __float_as_int(mx));
    }
  } else {
#pragma unroll
    for (int j = 0; j < TOC; ++j) {
      float* dst = &hout[(toc * TOC + j) * NTP + tn * TN];
      if (TN == 1) {
        dst[0] = fmaxf(acc[j][0], 0.0f);
      } else if (TN == 2) {
        float2 v = make_float2(fmaxf(acc[j][0], 0.0f),
                               fmaxf(acc[j][TN > 1 ? 1 : 0], 0.0f));
        *(float2*)dst = v;
      } else {
        float4 v = make_float4(fmaxf(acc[j][0], 0.0f),
                               fmaxf(acc[j][TN > 1 ? 1 : 0], 0.0f),
                               fmaxf(acc[j][TN > 2 ? 2 : 0], 0.0f),
                               fmaxf(acc[j][TN > 3 ? 3 : 0], 0.0f));
        *(float4*)dst = v;
      }
    }
  }
}

// ---------------------------------------------------------------------------
// Kernel B: one block per (b, s) sample point.
// Phase 1: 256 threads build per-chunk in-radius bitmasks for all 3 radii.
// Phase 2: wave s walks scale-s masks to build its ordered index list.
// Phase 3: per-scale MLP + max. Tiles: s0 NT=16, s1 NT=32, s2 2x NT=64.
// ---------------------------------------------------------------------------
__global__ __launch_bounds__(256) void msg_kernel(
    const float* __restrict__ pcd, const float* __restrict__ new_xyz,
    const float* __restrict__ wt,
    const float* __restrict__ b00, const float* __restrict__ b01,
    const float* __restrict__ b02, const float* __restrict__ b10,
    const float* __restrict__ b11, const float* __restrict__ b12,
    const float* __restrict__ b20, const float* __restrict__ b21,
    const float* __restrict__ b22,
    const float* __restrict__ wf, const float* __restrict__ bf,
    float* __restrict__ out) {
  __shared__ float hA[96 * 66];                  // 25344 B
  __shared__ float hB[64 * 66];                  // 16896 B
  __shared__ unsigned long long masks[3][64];    //  1536 B
  __shared__ int lists[176];                     // 16 + 32 + 128
  __shared__ float feat[320];

  const int bs = blockIdx.x;
  const int b = bs >> 9;
  const int tid = threadIdx.x;
  const int lane = tid & 63;
  const int wave = tid >> 6;
  const float* xb = pcd + (size_t)b * NPTS * 3;

  const float cx = new_xyz[(size_t)bs * 3 + 0];
  const float cy = new_xyz[(size_t)bs * 3 + 1];
  const float cz = new_xyz[(size_t)bs * 3 + 2];

  for (int c = tid; c < 320; c += 256) feat[c] = 0.0f;

  // ---- phase 1: all threads, 16 rounds, 3 ballots each -> 192 masks ----
  const float r2a = (float)(0.1 * 0.1);
  const float r2b = (float)(0.2 * 0.2);
  const float r2c = (float)(0.4 * 0.4);
#pragma unroll 4
  for (int j = 0; j < 16; ++j) {
    int i = (j << 8) | tid;
    const float* p = xb + i * 3;
    float dx = __fsub_rn(cx, p[0]);
    float dy = __fsub_rn(cy, p[1]);
    float dz = __fsub_rn(cz, p[2]);
    float sq = __fadd_rn(__fadd_rn(__fmul_rn(dx, dx), __fmul_rn(dy, dy)),
                         __fmul_rn(dz, dz));
    unsigned long long m0 = __ballot(sq < r2a);
    unsigned long long m1 = __ballot(sq < r2b);
    unsigned long long m2 = __ballot(sq < r2c);
    if (lane == 0) {
      int c = (j << 2) | wave;
      masks[0][c] = m0; masks[1][c] = m1; masks[2][c] = m2;
    }
  }
  __syncthreads();

  // ---- phase 2: wave s builds ordered list for scale s ----
  if (wave < 3) {
    const int ns  = (wave == 0) ? 16 : (wave == 1) ? 32 : 128;
    const int off = (wave == 0) ? 0  : (wave == 1) ? 16 : 48;
    int cnt = 0;
    for (int c = 0; c < 64; ++c) {
      unsigned long long m = masks[wave][c];
      if (m) {
        int bit = (int)((m >> lane) & 1ull);
        int pos = cnt + (int)__popcll(m & ((1ull << lane) - 1ull));
        if (bit && pos < ns) lists[off + pos] = (c << 6) | lane;
        cnt += (int)__popcll(m);
        if (cnt >= ns) break;
      }
    }
    if (cnt > ns) cnt = ns;
    int first = lists[off];              // center is always in-radius
    for (int k = cnt + lane; k < ns; k += 64) lists[off + k] = first;
  }
  __syncthreads();

  // ---- scale 0: ns=16, 3->32->32->64 -> feat[0:64) ----
  {
    if (tid < 16) {
      int j = lists[tid];
      const float* p = xb + j * 3;
      hA[0 * 18 + tid] = __fsub_rn(p[0], cx);
      hA[1 * 18 + tid] = __fsub_rn(p[1], cy);
      hA[2 * 18 + tid] = __fsub_rn(p[2], cz);
      hA[3 * 18 + tid] = 0.0f;
    }
    __syncthreads();
    layerT<4, 32, 16, 18, false>(wt + W00, b00, hA, hB, tid);  __syncthreads();
    layerT<32, 32, 16, 18, false>(wt + W01, b01, hB, hA, tid); __syncthreads();
    layerT<32, 64, 16, 18, true>(wt + W02, b02, hA, feat + 0, tid);
    __syncthreads();
  }
  // ---- scale 1: ns=32, 3->64->64->128 -> feat[64:192) ----
  {
    if (tid < 32) {
      int j = lists[16 + tid];
      const float* p = xb + j * 3;
      hA[0 * 34 + tid] = __fsub_rn(p[0], cx);
      hA[1 * 34 + tid] = __fsub_rn(p[1], cy);
      hA[2 * 34 + tid] = __fsub_rn(p[2], cz);
      hA[3 * 34 + tid] = 0.0f;
    }
    __syncthreads();
    layerT<4, 64, 32, 34, false>(wt + W10, b10, hA, hB, tid);  __syncthreads();
    layerT<64, 64, 32, 34, false>(wt + W11, b11, hB, hA, tid); __syncthreads();
    layerT<64, 128, 32, 34, true>(wt + W12, b12, hA, feat + 64, tid);
    __syncthreads();
  }
  // ---- scale 2: ns=128 in 2 tiles of 64, 3->64->96->128 -> feat[192:320) --
  for (int tile = 0; tile < 2; ++tile) {
    if (tid < 64) {
      int j = lists[48 + tile * 64 + tid];
      const float* p = xb + j * 3;
      hA[0 * 66 + tid] = __fsub_rn(p[0], cx);
      hA[1 * 66 + tid] = __fsub_rn(p[1], cy);
      hA[2 * 66 + tid] = __fsub_rn(p[2], cz);
      hA[3 * 66 + tid] = 0.0f;
    }
    __syncthreads();
    layerT<4, 64, 64, 66, false>(wt + W20, b20, hA, hB, tid);  __syncthreads();
    layerT<64, 96, 64, 66, false>(wt + W21, b21, hB, hA, tid); __syncthreads();
    layerT<96, 128, 64, 66, true>(wt + W22, b22, hA, feat + 192, tid);
    __syncthreads();
  }

  // ---- final linear 320 -> 1 ----
  if (tid < 64) {
    float s = 0.0f;
#pragma unroll
    for (int c = 0; c < 5; ++c) s += feat[tid + c * 64] * wf[tid + c * 64];
#pragma unroll
    for (int o = 32; o > 0; o >>= 1) s += __shfl_down(s, o);
    if (tid == 0) out[bs] = s + bf[0];
  }
}

extern "C" void kernel_launch(void* const* d_in, const int* in_sizes, int n_in,
                              void* d_out, int out_size, void* d_ws, size_t ws_size,
                              hipStream_t stream) {
  const float* pcd = (const float*)d_in[0];
  float* wsf = (float*)d_ws;
  float* new_xyz = wsf;                 // 8*512*3 = 12288 floats (48 KB)
  float* wt = wsf + 12288;              // 34432 floats (transposed weights)

  prep_kernel<<<(WT_TOTAL + 255) / 256, 256, 0, stream>>>(
      (const float*)d_in[1], (const float*)d_in[3], (const float*)d_in[5],
      (const float*)d_in[7], (const float*)d_in[9], (const float*)d_in[11],
      (const float*)d_in[13], (const float*)d_in[15], (const float*)d_in[17],
      wt);

  fps_kernel<<<BATCH, 256, 0, stream>>>(pcd, new_xyz);

  msg_kernel<<<BATCH * NSAMP, 256, 0, stream>>>(
      pcd, new_xyz, wt,
      (const float*)d_in[2],  (const float*)d_in[4],  (const float*)d_in[6],
      (const float*)d_in[8],  (const float*)d_in[10], (const float*)d_in[12],
      (const float*)d_in[14], (const float*)d_in[16], (const float*)d_in[18],
      (const float*)d_in[19], (const float*)d_in[20],
      (float*)d_out);
}